// Round 2
// baseline (1095.837 us; speedup 1.0000x reference)
//
#include <hip/hip_runtime.h>
#include <math.h>

#define B_ 16
#define L_ 1024
#define F_ 512
#define H_ 8
#define D_ 64
#define U_ 35

// ---------------- workspace layout (float elements) ----------------
// x aliases q: q is dead after scores_red; fill_x/scatter run later.
#define OFF_K     ((size_t)0)          // 8388608 floats (32 MB)
#define OFF_V     ((size_t)8388608)    // 8388608
#define OFF_Q     ((size_t)16777216)   // 8388608  (reused as X)
#define OFF_X     OFF_Q
#define OFF_S     ((size_t)25165824)   // 4587520 (17.5 MB)
#define OFF_M     ((size_t)29753344)   // 131072
#define OFF_KMEAN ((size_t)29884416)   // 8192
#define OFF_VMEAN ((size_t)29892608)   // 8192
#define OFF_CTX   ((size_t)29900800)   // 286720
#define OFF_IDX   ((size_t)30187520)   // 4480 ints
// total ~120.8 MB

// ---------------------------------------------------------------
// GEMM: C[m,n] = sum_k A[m,k] * W[n,k] + bias[n]
// A: (M,512) row-major; W: (512,512) row-major.
// head_layout=1: write to q-layout [b][h][l][d]; else row-major (m,512).
// ---------------------------------------------------------------
__global__ __launch_bounds__(256) void gemm_xwT(
    const float* __restrict__ A, const float* __restrict__ W,
    const float* __restrict__ bias, float* __restrict__ out,
    int head_layout)
{
    __shared__ float As[16][68];
    __shared__ float Bs[16][68];
    const int tid = threadIdx.x;
    const int tm = tid >> 4, tn = tid & 15;
    const int m0 = blockIdx.x * 64, n0 = blockIdx.y * 64;
    const int lr = tid >> 2;
    const int lc = (tid & 3) * 4;

    float acc[4][4];
#pragma unroll
    for (int i = 0; i < 4; i++)
#pragma unroll
        for (int j = 0; j < 4; j++) acc[i][j] = 0.f;

    for (int k0 = 0; k0 < 512; k0 += 16) {
        float4 a4 = *(const float4*)(A + (size_t)(m0 + lr) * 512 + k0 + lc);
        float4 w4 = *(const float4*)(W + (size_t)(n0 + lr) * 512 + k0 + lc);
        As[lc + 0][lr] = a4.x; As[lc + 1][lr] = a4.y; As[lc + 2][lr] = a4.z; As[lc + 3][lr] = a4.w;
        Bs[lc + 0][lr] = w4.x; Bs[lc + 1][lr] = w4.y; Bs[lc + 2][lr] = w4.z; Bs[lc + 3][lr] = w4.w;
        __syncthreads();
#pragma unroll
        for (int kk = 0; kk < 16; ++kk) {
            float4 a = *(const float4*)&As[kk][tm * 4];
            float4 b = *(const float4*)&Bs[kk][tn * 4];
            float av[4] = {a.x, a.y, a.z, a.w};
            float bvv[4] = {b.x, b.y, b.z, b.w};
#pragma unroll
            for (int i = 0; i < 4; i++)
#pragma unroll
                for (int j = 0; j < 4; j++) acc[i][j] = fmaf(av[i], bvv[j], acc[i][j]);
        }
        __syncthreads();
    }

    float4 bias4 = *(const float4*)(bias + n0 + tn * 4);
#pragma unroll
    for (int i = 0; i < 4; i++) {
        const int m = m0 + tm * 4 + i;
        float4 o;
        o.x = acc[i][0] + bias4.x;
        o.y = acc[i][1] + bias4.y;
        o.z = acc[i][2] + bias4.z;
        o.w = acc[i][3] + bias4.w;
        if (head_layout) {
            const int b = m >> 10, l = m & 1023;
            const int h = (n0 >> 6);           // n0 is a multiple of 64
            const int d = tn * 4;              // tiles are 64-wide
            *(float4*)(out + (((size_t)(b * H_ + h) * L_ + l) << 6) + d) = o;
        } else {
            *(float4*)(out + (size_t)m * 512 + n0 + tn * 4) = o;
        }
    }
}

// ---------------------------------------------------------------
// mean over L of a [bh][l][d] tensor -> [bh][d]
// ---------------------------------------------------------------
__global__ __launch_bounds__(256) void mean_over_L(
    const float* __restrict__ src, float* __restrict__ dst)
{
    const int bh = blockIdx.x;
    const int d = threadIdx.x & 63, g = threadIdx.x >> 6;
    const float* p = src + ((size_t)bh * L_ + g * 256) * 64 + d;
    float s = 0.f;
#pragma unroll 8
    for (int l = 0; l < 256; l++) s += p[(size_t)l * 64];
    __shared__ float red[4][64];
    red[g][d] = s;
    __syncthreads();
    if (threadIdx.x < 64) {
        const int dd = threadIdx.x;
        dst[(size_t)bh * 64 + dd] =
            (red[0][dd] + red[1][dd] + red[2][dd] + red[3][dd]) * (1.0f / 1024.0f);
    }
}

// ---------------------------------------------------------------
// M[l] = max_k(q_l . k_k) - q_l . kmean      (unscaled scores)
// grid: (16 qtiles, 128 bh), 256 threads
// ---------------------------------------------------------------
__global__ __launch_bounds__(256) void qk_rowmax(
    const float* __restrict__ q, const float* __restrict__ k,
    const float* __restrict__ kmean, float* __restrict__ Mout)
{
    __shared__ float Qs[64][68];   // [d][row]
    __shared__ float Ks[64][68];   // [d][row]
    __shared__ float km[64];
    __shared__ float Mred[64][17];
    const int bh = blockIdx.y;
    const int q0 = blockIdx.x * 64;
    const int tid = threadIdx.x;
    const int tm = tid >> 4, tn = tid & 15;
    const int lr = tid >> 2;
    const int lc0 = (tid & 3) * 4;

    if (tid < 64) km[tid] = kmean[(size_t)bh * 64 + tid];

    const float* qbase = q + ((size_t)bh * L_ + q0) * 64;
#pragma unroll
    for (int c = 0; c < 4; c++) {
        int lc = lc0 + c * 16;
        float4 v4 = *(const float4*)(qbase + (size_t)lr * 64 + lc);
        Qs[lc + 0][lr] = v4.x; Qs[lc + 1][lr] = v4.y; Qs[lc + 2][lr] = v4.z; Qs[lc + 3][lr] = v4.w;
    }

    float rmax[4] = {-INFINITY, -INFINITY, -INFINITY, -INFINITY};
    const float* kbase = k + (size_t)bh * L_ * 64;

    for (int kt = 0; kt < 16; ++kt) {
        __syncthreads();   // protect Ks against previous-iteration readers
#pragma unroll
        for (int c = 0; c < 4; c++) {
            int lc = lc0 + c * 16;
            float4 v4 = *(const float4*)(kbase + (size_t)(kt * 64 + lr) * 64 + lc);
            Ks[lc + 0][lr] = v4.x; Ks[lc + 1][lr] = v4.y; Ks[lc + 2][lr] = v4.z; Ks[lc + 3][lr] = v4.w;
        }
        __syncthreads();

        float sc[4][4];
#pragma unroll
        for (int i = 0; i < 4; i++)
#pragma unroll
            for (int j = 0; j < 4; j++) sc[i][j] = 0.f;

#pragma unroll 4
        for (int d = 0; d < 64; ++d) {
            float4 a = *(const float4*)&Qs[d][tm * 4];
            float4 b = *(const float4*)&Ks[d][tn * 4];
            float av[4] = {a.x, a.y, a.z, a.w};
            float bvv[4] = {b.x, b.y, b.z, b.w};
#pragma unroll
            for (int i = 0; i < 4; i++)
#pragma unroll
                for (int j = 0; j < 4; j++) sc[i][j] = fmaf(av[i], bvv[j], sc[i][j]);
        }
#pragma unroll
        for (int i = 0; i < 4; i++) {
            float mx = fmaxf(fmaxf(sc[i][0], sc[i][1]), fmaxf(sc[i][2], sc[i][3]));
            rmax[i] = fmaxf(rmax[i], mx);
        }
    }

#pragma unroll
    for (int i = 0; i < 4; i++) Mred[tm * 4 + i][tn] = rmax[i];
    __syncthreads();

    if (tid < 64) {
        float m = -INFINITY;
#pragma unroll
        for (int t = 0; t < 16; t++) m = fmaxf(m, Mred[tid][t]);
        float dot = 0.f;
#pragma unroll 4
        for (int d = 0; d < 64; ++d) dot = fmaf(Qs[d][tid], km[d], dot);
        Mout[(size_t)bh * L_ + q0 + tid] = m - dot;
    }
}

// ---------------------------------------------------------------
// top-35 of M[1024] per (b,h); iterative argmax, ties -> lowest index
// ---------------------------------------------------------------
__global__ __launch_bounds__(256) void topk35(
    const float* __restrict__ Min, int* __restrict__ idx_out)
{
    const int bh = blockIdx.x;
    const int tid = threadIdx.x;
    __shared__ float vals[1024];
    __shared__ float wv[4];
    __shared__ int wi[4];
    for (int i = tid; i < 1024; i += 256) vals[i] = Min[(size_t)bh * 1024 + i];
    __syncthreads();
    for (int it = 0; it < U_; ++it) {
        float bv = -INFINITY; int bi = 1 << 30;
        for (int i = tid; i < 1024; i += 256) {
            float x = vals[i];
            if (x > bv) { bv = x; bi = i; }
        }
#pragma unroll
        for (int off = 32; off; off >>= 1) {
            float ov = __shfl_down(bv, off);
            int   oi = __shfl_down(bi, off);
            if (ov > bv || (ov == bv && oi < bi)) { bv = ov; bi = oi; }
        }
        if ((tid & 63) == 0) { wv[tid >> 6] = bv; wi[tid >> 6] = bi; }
        __syncthreads();
        if (tid == 0) {
#pragma unroll
            for (int w = 1; w < 4; ++w) {
                if (wv[w] > bv || (wv[w] == bv && wi[w] < bi)) { bv = wv[w]; bi = wi[w]; }
            }
            idx_out[bh * U_ + it] = bi;
            vals[bi] = -INFINITY;
        }
        __syncthreads();
    }
}

// ---------------------------------------------------------------
// S[u][k] = (q[idx_u] . k_k) / 8, masked -> -inf ; grid 128 (bh)
// ---------------------------------------------------------------
__global__ __launch_bounds__(256) void scores_red(
    const float* __restrict__ q, const float* __restrict__ k,
    const int* __restrict__ idx, const int* __restrict__ mask,
    float* __restrict__ S)
{
    __shared__ float Qs[64][36];   // [d][u], u=35 padded with zeros
    __shared__ float Ks[64][68];   // [d][key]
    const int bh = blockIdx.x;
    const int b = bh >> 3;
    const int tid = threadIdx.x;
    const int tk = tid & 63, tg = tid >> 6;
    const int lr = tid >> 2, lc0 = (tid & 3) * 4;

    for (int t = tid; t < 36 * 64; t += 256) {
        int u = t >> 6, d = t & 63;
        float val = 0.f;
        if (u < U_) {
            int l = idx[bh * U_ + u];
            val = q[((size_t)bh * L_ + l) * 64 + d];
        }
        Qs[d][u] = val;
    }

    const float* kbase = k + (size_t)bh * L_ * 64;
    float acc[9];
    for (int kt = 0; kt < 16; ++kt) {
        if (kt) __syncthreads();
#pragma unroll
        for (int c = 0; c < 4; c++) {
            int lc = lc0 + c * 16;
            float4 v4 = *(const float4*)(kbase + (size_t)(kt * 64 + lr) * 64 + lc);
            Ks[lc + 0][lr] = v4.x; Ks[lc + 1][lr] = v4.y; Ks[lc + 2][lr] = v4.z; Ks[lc + 3][lr] = v4.w;
        }
        __syncthreads();
#pragma unroll
        for (int j = 0; j < 9; j++) acc[j] = 0.f;
#pragma unroll 4
        for (int d = 0; d < 64; ++d) {
            float kv = Ks[d][tk];
#pragma unroll
            for (int j = 0; j < 9; j++) acc[j] = fmaf(Qs[d][tg + 4 * j], kv, acc[j]);
        }
        const int kcol = kt * 64 + tk;
        const bool msk = (mask[b * L_ + kcol] == 0);
#pragma unroll
        for (int j = 0; j < 9; j++) {
            int u = tg + 4 * j;
            if (u < U_)
                S[((size_t)bh * U_ + u) * 1024 + kcol] = msk ? -INFINITY : acc[j] * 0.125f;
        }
    }
}

// ---------------------------------------------------------------
// softmax over 1024 per row; grid 4480 rows
// ---------------------------------------------------------------
__global__ __launch_bounds__(256) void softmax_rows(float* __restrict__ S)
{
    const size_t base = (size_t)blockIdx.x * 1024;
    const int tid = threadIdx.x;
    __shared__ float redm[4];
    __shared__ float reds[4];
    float4 v = *(const float4*)(S + base + tid * 4);
    float mx = fmaxf(fmaxf(v.x, v.y), fmaxf(v.z, v.w));
#pragma unroll
    for (int off = 32; off; off >>= 1) mx = fmaxf(mx, __shfl_down(mx, off));
    if ((tid & 63) == 0) redm[tid >> 6] = mx;
    __syncthreads();
    mx = fmaxf(fmaxf(redm[0], redm[1]), fmaxf(redm[2], redm[3]));
    float e0 = __expf(v.x - mx), e1 = __expf(v.y - mx);
    float e2 = __expf(v.z - mx), e3 = __expf(v.w - mx);
    float s = e0 + e1 + e2 + e3;
#pragma unroll
    for (int off = 32; off; off >>= 1) s += __shfl_down(s, off);
    if ((tid & 63) == 0) reds[tid >> 6] = s;
    __syncthreads();
    s = reds[0] + reds[1] + reds[2] + reds[3];
    const float inv = 1.0f / s;
    float4 o; o.x = e0 * inv; o.y = e1 * inv; o.z = e2 * inv; o.w = e3 * inv;
    *(float4*)(S + base + tid * 4) = o;
}

// ---------------------------------------------------------------
// ctx[u][d] = sum_k S[u][k] * v[k][d] ; grid 128 (bh)
// ---------------------------------------------------------------
__global__ __launch_bounds__(256) void ctx_gemm(
    const float* __restrict__ S, const float* __restrict__ v,
    float* __restrict__ ctx)
{
    __shared__ float Vs[64][68];   // [key][d]
    __shared__ float Wt[36][64];   // [u][key], u=35 padded zero
    const int bh = blockIdx.x;
    const int tid = threadIdx.x;
    const int td = tid & 63, tg = tid >> 6;
    const int lr = tid >> 2, lc0 = (tid & 3) * 4;
    float acc[9];
#pragma unroll
    for (int j = 0; j < 9; j++) acc[j] = 0.f;
    const float* vbase = v + (size_t)bh * L_ * 64;
    const float* Sbase = S + (size_t)bh * U_ * 1024;
    for (int kt = 0; kt < 16; ++kt) {
        if (kt) __syncthreads();
#pragma unroll
        for (int c = 0; c < 4; c++) {
            int lc = lc0 + c * 16;
            float4 x4 = *(const float4*)(vbase + (size_t)(kt * 64 + lr) * 64 + lc);
            *(float4*)&Vs[lr][lc] = x4;
        }
        for (int t = tid; t < 36 * 64; t += 256) {
            int u = t >> 6, kk = t & 63;
            Wt[u][kk] = (u < U_) ? Sbase[(size_t)u * 1024 + kt * 64 + kk] : 0.f;
        }
        __syncthreads();
#pragma unroll 2
        for (int kk = 0; kk < 64; ++kk) {
            float vv = Vs[kk][td];
#pragma unroll
            for (int j = 0; j < 9; j++) acc[j] = fmaf(Wt[tg + 4 * j][kk], vv, acc[j]);
        }
    }
#pragma unroll
    for (int j = 0; j < 9; j++) {
        int u = tg + 4 * j;
        if (u < U_) ctx[((size_t)bh * U_ + u) * 64 + td] = acc[j];
    }
}

// ---------------------------------------------------------------
// x[b][l][h*64+d] = vmean[b*8+h][d]   (broadcast fill)
// ---------------------------------------------------------------
__global__ void fill_x_kernel(const float* __restrict__ vmean, float* __restrict__ x)
{
    const size_t i = (size_t)blockIdx.x * 256 + threadIdx.x;
    const int n = (int)(i & 511);
    const int b = (int)(i >> 19);   // / (1024*512)
    x[i] = vmean[((b << 3) + (n >> 6)) * 64 + (n & 63)];
}

// ---------------------------------------------------------------
// scatter ctx rows into x ; grid 4480, block 64
// ---------------------------------------------------------------
__global__ void scatter_ctx_kernel(const float* __restrict__ ctx, const int* __restrict__ idx,
                                   float* __restrict__ x)
{
    const int r = blockIdx.x;              // bh*35 + u
    const int bh = r / U_;
    const int b = bh >> 3, h = bh & 7;
    const int l = idx[r];
    x[(((size_t)b * L_ + l) << 9) + (h << 6) + threadIdx.x] = ctx[(size_t)r * 64 + threadIdx.x];
}

// ---------------------------------------------------------------
extern "C" void kernel_launch(void* const* d_in, const int* in_sizes, int n_in,
                              void* d_out, int out_size, void* d_ws, size_t ws_size,
                              hipStream_t stream)
{
    (void)in_sizes; (void)n_in; (void)out_size; (void)ws_size;
    const float* query = (const float*)d_in[0];
    const float* key   = (const float*)d_in[1];
    const float* value = (const float*)d_in[2];
    const int*   mask  = (const int*)d_in[3];
    const float* Wq = (const float*)d_in[4];
    const float* bq = (const float*)d_in[5];
    const float* Wk = (const float*)d_in[6];
    const float* bk = (const float*)d_in[7];
    const float* Wv = (const float*)d_in[8];
    const float* bvp = (const float*)d_in[9];
    const float* Wo = (const float*)d_in[10];
    const float* bo = (const float*)d_in[11];
    float* out = (float*)d_out;

    float* ws = (float*)d_ws;
    float* q     = ws + OFF_Q;
    float* k     = ws + OFF_K;
    float* v     = ws + OFF_V;
    float* x     = ws + OFF_X;     // aliases q (q dead after scores_red)
    float* Marr  = ws + OFF_M;
    float* kmean = ws + OFF_KMEAN;
    float* vmean = ws + OFF_VMEAN;
    float* ctx   = ws + OFF_CTX;
    float* S     = ws + OFF_S;
    int*   idx   = (int*)(ws + OFF_IDX);

    const dim3 ggemm(256, 8);

    // projections into head-layout
    gemm_xwT<<<ggemm, 256, 0, stream>>>(query, Wq, bq, q, 1);
    gemm_xwT<<<ggemm, 256, 0, stream>>>(key,   Wk, bk, k, 1);
    gemm_xwT<<<ggemm, 256, 0, stream>>>(value, Wv, bvp, v, 1);

    // per-(b,h) means
    mean_over_L<<<128, 256, 0, stream>>>(k, kmean);
    mean_over_L<<<128, 256, 0, stream>>>(v, vmean);

    // sparsity measure M and top-35 per (b,h)
    qk_rowmax<<<dim3(16, 128), 256, 0, stream>>>(q, k, kmean, Marr);
    topk35<<<128, 256, 0, stream>>>(Marr, idx);

    // reduced attention
    scores_red<<<128, 256, 0, stream>>>(q, k, idx, mask, S);
    softmax_rows<<<B_ * H_ * U_, 256, 0, stream>>>(S);
    ctx_gemm<<<128, 256, 0, stream>>>(S, v, ctx);

    // assemble x (overwrites q region) and final projection
    fill_x_kernel<<<32768, 256, 0, stream>>>(vmean, x);
    scatter_ctx_kernel<<<B_ * H_ * U_, 64, 0, stream>>>(ctx, idx, x);
    gemm_xwT<<<ggemm, 256, 0, stream>>>(x, Wo, bo, out, 0);
}

// Round 3
// 622.078 us; speedup vs baseline: 1.7616x; 1.7616x over previous
//
#include <hip/hip_runtime.h>
#include <math.h>

#define B_ 16
#define L_ 1024
#define H_ 8
#define U_ 35

typedef float f32x4 __attribute__((ext_vector_type(4)));
typedef short bf16x8 __attribute__((ext_vector_type(8)));

__device__ __forceinline__ unsigned short f2bf(float x) {
    unsigned int u = __float_as_uint(x);
    u += 0x7FFFu + ((u >> 16) & 1u);      // round-to-nearest-even
    return (unsigned short)(u >> 16);
}
__device__ __forceinline__ float bf2f(unsigned short b) {
    return __uint_as_float(((unsigned int)b) << 16);
}

#define MFMA(a, b, c) __builtin_amdgcn_mfma_f32_16x16x32_bf16((a), (b), (c), 0, 0, 0)

// ---------------- workspace layout (float-element offsets) ----------------
// v fp32 | q_hi,q_lo (x fp32 aliases) | k_hi,k_lo | S (Wq/Wk/Wv splits alias) |
// M | kmean | vmean | ctx | idx | Wo splits
#define OFF_V      ((size_t)0)           // 8388608 f
#define OFF_QHI    ((size_t)8388608)     // 4194304 f-units (8388608 ushort)
#define OFF_QLO    ((size_t)12582912)    // 4194304
#define OFF_X      OFF_QHI               // x fp32 aliases q_hi/q_lo (dead then)
#define OFF_KHI    ((size_t)16777216)    // 4194304
#define OFF_KLO    ((size_t)20971520)    // 4194304
#define OFF_S      ((size_t)25165824)    // 4587520
#define OFF_WQH    OFF_S                 // W splits alias S (dead before scores)
#define OFF_WQL    ((size_t)(OFF_S + 131072))
#define OFF_WKH    ((size_t)(OFF_S + 262144))
#define OFF_WKL    ((size_t)(OFF_S + 393216))
#define OFF_WVH    ((size_t)(OFF_S + 524288))
#define OFF_WVL    ((size_t)(OFF_S + 655360))
#define OFF_M      ((size_t)29753344)    // 131072
#define OFF_KMEAN  ((size_t)29884416)    // 8192
#define OFF_VMEAN  ((size_t)29892608)    // 8192
#define OFF_CTX    ((size_t)29900800)    // 286720
#define OFF_IDX    ((size_t)30187520)    // 4480
#define OFF_WOH    ((size_t)30192000)    // 131072
#define OFF_WOL    ((size_t)30323072)    // 131072
// end 30454144 f = ~121.8 MB

// ---------------------------------------------------------------
// split one 512x512 fp32 weight into hi/lo bf16 bits; grid 1024 x 256
// ---------------------------------------------------------------
__global__ __launch_bounds__(256) void split_w_kernel(
    const float* __restrict__ W, unsigned short* __restrict__ hi,
    unsigned short* __restrict__ lo)
{
    int i = blockIdx.x * 256 + threadIdx.x;
    float x = W[i];
    unsigned short h = f2bf(x);
    hi[i] = h;
    lo[i] = f2bf(x - bf2f(h));
}

// ---------------------------------------------------------------
// bf16x2 MFMA GEMM: C[m,n] = sum_k A[m,k]*W[n,k] + bias[n]
// A fp32 (Mx512 row-major, split in-kernel); W pre-split hi/lo bf16 (512x512).
// head_layout=1: write head layout [b][h][l][d]; outf / (ohi,olo) optional.
// Block 128x128 tile, 4 waves of 64x64, BK=32, 16x16x32 MFMA x3 splits.
// ---------------------------------------------------------------
__global__ __launch_bounds__(256) void gemm_mfma(
    const float* __restrict__ A,
    const unsigned short* __restrict__ Whi, const unsigned short* __restrict__ Wlo,
    const float* __restrict__ bias,
    float* __restrict__ outf,
    unsigned short* __restrict__ ohi, unsigned short* __restrict__ olo,
    const int head_layout)
{
    __shared__ unsigned short Ah[128][40];
    __shared__ unsigned short Al[128][40];
    __shared__ unsigned short Bh[128][40];
    __shared__ unsigned short Bl[128][40];
    const int tid = threadIdx.x, lane = tid & 63, wave = tid >> 6;
    const int m0 = blockIdx.x * 128, n0 = blockIdx.y * 128;
    const int wm = (wave >> 1) * 64, wn = (wave & 1) * 64;

    f32x4 zero4 = {0.f, 0.f, 0.f, 0.f};
    f32x4 acc[4][4];
#pragma unroll
    for (int i = 0; i < 4; i++)
#pragma unroll
        for (int j = 0; j < 4; j++) acc[i][j] = zero4;

    const int ar = tid >> 3, ac = (tid & 7) * 4;     // A-stage map
    const int br = tid >> 2, bc = (tid & 3) * 8;     // B-stage map
    const int kc = (lane >> 4) * 8;                  // frag k-offset
    const int fr = lane & 15;                        // frag row

    for (int k0 = 0; k0 < 512; k0 += 32) {
        if (k0) __syncthreads();
        // stage A fp32 -> hi/lo bf16 (128 x 32)
#pragma unroll
        for (int p = 0; p < 4; ++p) {
            float4 a4 = *(const float4*)(A + (size_t)(m0 + ar + p * 32) * 512 + k0 + ac);
            ushort4 h4, l4;
            h4.x = f2bf(a4.x); l4.x = f2bf(a4.x - bf2f(h4.x));
            h4.y = f2bf(a4.y); l4.y = f2bf(a4.y - bf2f(h4.y));
            h4.z = f2bf(a4.z); l4.z = f2bf(a4.z - bf2f(h4.z));
            h4.w = f2bf(a4.w); l4.w = f2bf(a4.w - bf2f(h4.w));
            *(ushort4*)&Ah[ar + p * 32][ac] = h4;
            *(ushort4*)&Al[ar + p * 32][ac] = l4;
        }
        // stage B from pre-split W (128 x 32)
#pragma unroll
        for (int p = 0; p < 2; ++p) {
            size_t off = (size_t)(n0 + br + p * 64) * 512 + k0 + bc;
            *(uint4*)&Bh[br + p * 64][bc] = *(const uint4*)(Whi + off);
            *(uint4*)&Bl[br + p * 64][bc] = *(const uint4*)(Wlo + off);
        }
        __syncthreads();

        bf16x8 ah[4], al[4];
#pragma unroll
        for (int mi = 0; mi < 4; ++mi) {
            int row = wm + mi * 16 + fr;
            ah[mi] = *(bf16x8*)&Ah[row][kc];
            al[mi] = *(bf16x8*)&Al[row][kc];
        }
#pragma unroll
        for (int ni = 0; ni < 4; ++ni) {
            int rn = wn + ni * 16 + fr;
            bf16x8 bh8 = *(bf16x8*)&Bh[rn][kc];
            bf16x8 bl8 = *(bf16x8*)&Bl[rn][kc];
#pragma unroll
            for (int mi = 0; mi < 4; ++mi) {
                acc[mi][ni] = MFMA(ah[mi], bh8, acc[mi][ni]);
                acc[mi][ni] = MFMA(ah[mi], bl8, acc[mi][ni]);
                acc[mi][ni] = MFMA(al[mi], bh8, acc[mi][ni]);
            }
        }
    }

    // epilogue: C row=(lane>>4)*4+reg, col=lane&15 (verified m89/m91 layout)
    const int col = lane & 15, rq = (lane >> 4) * 4;
#pragma unroll
    for (int ni = 0; ni < 4; ++ni) {
        int n = n0 + wn + ni * 16 + col;
        float bn = bias[n];
#pragma unroll
        for (int mi = 0; mi < 4; ++mi) {
#pragma unroll
            for (int r = 0; r < 4; ++r) {
                int m = m0 + wm + mi * 16 + rq + r;
                float val = acc[mi][ni][r] + bn;
                if (head_layout) {
                    size_t off = ((size_t)((m >> 10) * H_ + (n >> 6)) * L_ + (m & 1023)) * 64 + (n & 63);
                    if (outf) outf[off] = val;
                    if (ohi) {
                        unsigned short h = f2bf(val);
                        ohi[off] = h;
                        olo[off] = f2bf(val - bf2f(h));
                    }
                } else {
                    outf[(size_t)m * 512 + n] = val;
                }
            }
        }
    }
}

// ---------------------------------------------------------------
// mean over L of fp32 [bh][l][d] -> [bh][d]
// ---------------------------------------------------------------
__global__ __launch_bounds__(256) void mean_over_L(
    const float* __restrict__ src, float* __restrict__ dst)
{
    const int bh = blockIdx.x;
    const int d = threadIdx.x & 63, g = threadIdx.x >> 6;
    const float* p = src + ((size_t)bh * L_ + g * 256) * 64 + d;
    float s = 0.f;
#pragma unroll 8
    for (int l = 0; l < 256; l++) s += p[(size_t)l * 64];
    __shared__ float red[4][64];
    red[g][d] = s;
    __syncthreads();
    if (threadIdx.x < 64) {
        const int dd = threadIdx.x;
        dst[(size_t)bh * 64 + dd] =
            (red[0][dd] + red[1][dd] + red[2][dd] + red[3][dd]) * (1.0f / 1024.0f);
    }
}

// same, from hi/lo bf16 pair
__global__ __launch_bounds__(256) void mean_over_L_bf(
    const unsigned short* __restrict__ hi, const unsigned short* __restrict__ lo,
    float* __restrict__ dst)
{
    const int bh = blockIdx.x;
    const int d = threadIdx.x & 63, g = threadIdx.x >> 6;
    size_t base = ((size_t)bh * L_ + g * 256) * 64 + d;
    float s = 0.f;
#pragma unroll 8
    for (int l = 0; l < 256; l++) {
        size_t o = base + (size_t)l * 64;
        s += bf2f(hi[o]) + bf2f(lo[o]);
    }
    __shared__ float red[4][64];
    red[g][d] = s;
    __syncthreads();
    if (threadIdx.x < 64) {
        const int dd = threadIdx.x;
        dst[(size_t)bh * 64 + dd] =
            (red[0][dd] + red[1][dd] + red[2][dd] + red[3][dd]) * (1.0f / 1024.0f);
    }
}

// ---------------------------------------------------------------
// M[l] = max_k(q_l . k_k) - q_l . kmean via bf16x2 MFMA
// grid (16 qtiles, 128 bh); 64 q-rows/block, key chunks of 128 (32/wave)
// ---------------------------------------------------------------
__global__ __launch_bounds__(256) void qk_rowmax_mfma(
    const unsigned short* __restrict__ qhi, const unsigned short* __restrict__ qlo,
    const unsigned short* __restrict__ khi, const unsigned short* __restrict__ klo,
    const float* __restrict__ kmean, float* __restrict__ Mout)
{
    __shared__ unsigned short Qh[64][72], Ql[64][72];
    __shared__ unsigned short Kh[128][72], Kl[128][72];
    __shared__ float Mred[64][4];
    __shared__ float km[64];
    const int bh = blockIdx.y, q0 = blockIdx.x * 64;
    const int tid = threadIdx.x, lane = tid & 63, wave = tid >> 6;

    if (tid < 64) km[tid] = kmean[bh * 64 + tid];
    {
        int r = tid >> 2, c = (tid & 3) * 16;
        size_t off = ((size_t)bh * L_ + q0 + r) * 64 + c;
        *(uint4*)&Qh[r][c]     = *(const uint4*)(qhi + off);
        *(uint4*)&Qh[r][c + 8] = *(const uint4*)(qhi + off + 8);
        *(uint4*)&Ql[r][c]     = *(const uint4*)(qlo + off);
        *(uint4*)&Ql[r][c + 8] = *(const uint4*)(qlo + off + 8);
    }

    float rmax[4][4];
#pragma unroll
    for (int mi = 0; mi < 4; ++mi)
#pragma unroll
        for (int r = 0; r < 4; ++r) rmax[mi][r] = -INFINITY;

    const size_t kb = (size_t)bh * L_ * 64;
    const int sr = tid >> 2, sc = (tid & 3) * 16;
    const int fr = lane & 15;
    f32x4 zero4 = {0.f, 0.f, 0.f, 0.f};

    for (int kt = 0; kt < 8; ++kt) {
        __syncthreads();   // covers Q/km stage (kt=0) and prev-iter readers
        {
            size_t off = kb + (size_t)(kt * 128 + sr) * 64 + sc;
            *(uint4*)&Kh[sr][sc]          = *(const uint4*)(khi + off);
            *(uint4*)&Kh[sr][sc + 8]      = *(const uint4*)(khi + off + 8);
            *(uint4*)&Kl[sr][sc]          = *(const uint4*)(klo + off);
            *(uint4*)&Kl[sr][sc + 8]      = *(const uint4*)(klo + off + 8);
            size_t off2 = off + 64 * 64;
            *(uint4*)&Kh[sr + 64][sc]     = *(const uint4*)(khi + off2);
            *(uint4*)&Kh[sr + 64][sc + 8] = *(const uint4*)(khi + off2 + 8);
            *(uint4*)&Kl[sr + 64][sc]     = *(const uint4*)(klo + off2);
            *(uint4*)&Kl[sr + 64][sc + 8] = *(const uint4*)(klo + off2 + 8);
        }
        __syncthreads();

        f32x4 acc[4][2];
#pragma unroll
        for (int mi = 0; mi < 4; ++mi) { acc[mi][0] = zero4; acc[mi][1] = zero4; }

#pragma unroll
        for (int ks = 0; ks < 2; ++ks) {
            int kcol = ks * 32 + (lane >> 4) * 8;
            bf16x8 ah[4], al[4];
#pragma unroll
            for (int mi = 0; mi < 4; ++mi) {
                int row = mi * 16 + fr;
                ah[mi] = *(bf16x8*)&Qh[row][kcol];
                al[mi] = *(bf16x8*)&Ql[row][kcol];
            }
#pragma unroll
            for (int ni = 0; ni < 2; ++ni) {
                int krow = wave * 32 + ni * 16 + fr;
                bf16x8 bh8 = *(bf16x8*)&Kh[krow][kcol];
                bf16x8 bl8 = *(bf16x8*)&Kl[krow][kcol];
#pragma unroll
                for (int mi = 0; mi < 4; ++mi) {
                    acc[mi][ni] = MFMA(ah[mi], bh8, acc[mi][ni]);
                    acc[mi][ni] = MFMA(ah[mi], bl8, acc[mi][ni]);
                    acc[mi][ni] = MFMA(al[mi], bh8, acc[mi][ni]);
                }
            }
        }
#pragma unroll
        for (int mi = 0; mi < 4; ++mi)
#pragma unroll
            for (int r = 0; r < 4; ++r)
                rmax[mi][r] = fmaxf(rmax[mi][r], fmaxf(acc[mi][0][r], acc[mi][1][r]));
    }

    // max over the 16 columns held across lanes of each 16-group
#pragma unroll
    for (int mi = 0; mi < 4; ++mi)
#pragma unroll
        for (int r = 0; r < 4; ++r) {
            float v = rmax[mi][r];
            v = fmaxf(v, __shfl_xor(v, 1));
            v = fmaxf(v, __shfl_xor(v, 2));
            v = fmaxf(v, __shfl_xor(v, 4));
            v = fmaxf(v, __shfl_xor(v, 8));
            rmax[mi][r] = v;
        }
    if ((lane & 15) == 0) {
        int quad = lane >> 4;
#pragma unroll
        for (int mi = 0; mi < 4; ++mi)
#pragma unroll
            for (int r = 0; r < 4; ++r)
                Mred[mi * 16 + quad * 4 + r][wave] = rmax[mi][r];
    }
    __syncthreads();
    if (tid < 64) {
        float mx = fmaxf(fmaxf(Mred[tid][0], Mred[tid][1]),
                         fmaxf(Mred[tid][2], Mred[tid][3]));
        float dot = 0.f;
#pragma unroll 4
        for (int d = 0; d < 64; ++d)
            dot = fmaf(bf2f(Qh[tid][d]) + bf2f(Ql[tid][d]), km[d], dot);
        Mout[(size_t)bh * L_ + q0 + tid] = mx - dot;
    }
}

// ---------------------------------------------------------------
// top-35 of M[1024] per (b,h); iterative argmax, ties -> lowest index
// ---------------------------------------------------------------
__global__ __launch_bounds__(256) void topk35(
    const float* __restrict__ Min, int* __restrict__ idx_out)
{
    const int bh = blockIdx.x;
    const int tid = threadIdx.x;
    __shared__ float vals[1024];
    __shared__ float wv[4];
    __shared__ int wi[4];
    for (int i = tid; i < 1024; i += 256) vals[i] = Min[(size_t)bh * 1024 + i];
    __syncthreads();
    for (int it = 0; it < U_; ++it) {
        float bv = -INFINITY; int bi = 1 << 30;
        for (int i = tid; i < 1024; i += 256) {
            float x = vals[i];
            if (x > bv) { bv = x; bi = i; }
        }
#pragma unroll
        for (int off = 32; off; off >>= 1) {
            float ov = __shfl_down(bv, off);
            int   oi = __shfl_down(bi, off);
            if (ov > bv || (ov == bv && oi < bi)) { bv = ov; bi = oi; }
        }
        if ((tid & 63) == 0) { wv[tid >> 6] = bv; wi[tid >> 6] = bi; }
        __syncthreads();
        if (tid == 0) {
#pragma unroll
            for (int w = 1; w < 4; ++w) {
                if (wv[w] > bv || (wv[w] == bv && wi[w] < bi)) { bv = wv[w]; bi = wi[w]; }
            }
            idx_out[bh * U_ + it] = bi;
            vals[bi] = -INFINITY;
        }
        __syncthreads();
    }
}

// ---------------------------------------------------------------
// S[u][k] = (q[idx_u] . k_k)/8 masked; q,k reconstructed hi+lo; grid 128
// ---------------------------------------------------------------
__global__ __launch_bounds__(256) void scores_red(
    const unsigned short* __restrict__ qhi, const unsigned short* __restrict__ qlo,
    const unsigned short* __restrict__ khi, const unsigned short* __restrict__ klo,
    const int* __restrict__ idx, const int* __restrict__ mask,
    float* __restrict__ S)
{
    __shared__ float Qs[64][36];
    __shared__ float Ks[64][68];
    const int bh = blockIdx.x;
    const int b = bh >> 3;
    const int tid = threadIdx.x;
    const int tk = tid & 63, tg = tid >> 6;

    for (int t = tid; t < 36 * 64; t += 256) {
        int u = t >> 6, d = t & 63;
        float val = 0.f;
        if (u < U_) {
            int l = idx[bh * U_ + u];
            size_t off = ((size_t)bh * L_ + l) * 64 + d;
            val = bf2f(qhi[off]) + bf2f(qlo[off]);
        }
        Qs[d][u] = val;
    }

    const size_t kb = (size_t)bh * L_ * 64;
    const int sr = tid >> 2, sc = (tid & 3) * 16;
    float acc[9];
    for (int kt = 0; kt < 16; ++kt) {
        if (kt) __syncthreads();
        {
            size_t off = kb + (size_t)(kt * 64 + sr) * 64 + sc;
            uint4 h0 = *(const uint4*)(khi + off);
            uint4 h1 = *(const uint4*)(khi + off + 8);
            uint4 l0 = *(const uint4*)(klo + off);
            uint4 l1 = *(const uint4*)(klo + off + 8);
            unsigned short hv[16], lv[16];
            *(uint4*)hv = h0; *(uint4*)(hv + 8) = h1;
            *(uint4*)lv = l0; *(uint4*)(lv + 8) = l1;
#pragma unroll
            for (int i = 0; i < 16; ++i)
                Ks[sc + i][sr] = bf2f(hv[i]) + bf2f(lv[i]);
        }
        __syncthreads();
#pragma unroll
        for (int j = 0; j < 9; j++) acc[j] = 0.f;
#pragma unroll 4
        for (int d = 0; d < 64; ++d) {
            float kv = Ks[d][tk];
#pragma unroll
            for (int j = 0; j < 9; j++) acc[j] = fmaf(Qs[d][tg + 4 * j], kv, acc[j]);
        }
        const int kcol = kt * 64 + tk;
        const bool msk = (mask[b * L_ + kcol] == 0);
#pragma unroll
        for (int j = 0; j < 9; j++) {
            int u = tg + 4 * j;
            if (u < U_)
                S[((size_t)bh * U_ + u) * 1024 + kcol] = msk ? -INFINITY : acc[j] * 0.125f;
        }
    }
}

// ---------------------------------------------------------------
// softmax over 1024 per row; grid 4480 rows
// ---------------------------------------------------------------
__global__ __launch_bounds__(256) void softmax_rows(float* __restrict__ S)
{
    const size_t base = (size_t)blockIdx.x * 1024;
    const int tid = threadIdx.x;
    __shared__ float redm[4];
    __shared__ float reds[4];
    float4 v = *(const float4*)(S + base + tid * 4);
    float mx = fmaxf(fmaxf(v.x, v.y), fmaxf(v.z, v.w));
#pragma unroll
    for (int off = 32; off; off >>= 1) mx = fmaxf(mx, __shfl_down(mx, off));
    if ((tid & 63) == 0) redm[tid >> 6] = mx;
    __syncthreads();
    mx = fmaxf(fmaxf(redm[0], redm[1]), fmaxf(redm[2], redm[3]));
    float e0 = __expf(v.x - mx), e1 = __expf(v.y - mx);
    float e2 = __expf(v.z - mx), e3 = __expf(v.w - mx);
    float s = e0 + e1 + e2 + e3;
#pragma unroll
    for (int off = 32; off; off >>= 1) s += __shfl_down(s, off);
    if ((tid & 63) == 0) reds[tid >> 6] = s;
    __syncthreads();
    s = reds[0] + reds[1] + reds[2] + reds[3];
    const float inv = 1.0f / s;
    float4 o; o.x = e0 * inv; o.y = e1 * inv; o.z = e2 * inv; o.w = e3 * inv;
    *(float4*)(S + base + tid * 4) = o;
}

// ---------------------------------------------------------------
// ctx[u][d] = sum_k S[u][k] * v[k][d] ; grid 128 (bh)
// ---------------------------------------------------------------
__global__ __launch_bounds__(256) void ctx_gemm(
    const float* __restrict__ S, const float* __restrict__ v,
    float* __restrict__ ctx)
{
    __shared__ float Vs[64][68];
    __shared__ float Wt[36][64];
    const int bh = blockIdx.x;
    const int tid = threadIdx.x;
    const int td = tid & 63, tg = tid >> 6;
    const int lr = tid >> 2, lc0 = (tid & 3) * 4;
    float acc[9];
#pragma unroll
    for (int j = 0; j < 9; j++) acc[j] = 0.f;
    const float* vbase = v + (size_t)bh * L_ * 64;
    const float* Sbase = S + (size_t)bh * U_ * 1024;
    for (int kt = 0; kt < 16; ++kt) {
        if (kt) __syncthreads();
#pragma unroll
        for (int c = 0; c < 4; c++) {
            int lc = lc0 + c * 16;
            float4 x4 = *(const float4*)(vbase + (size_t)(kt * 64 + lr) * 64 + lc);
            *(float4*)&Vs[lr][lc] = x4;
        }
        for (int t = tid; t < 36 * 64; t += 256) {
            int u = t >> 6, kk = t & 63;
            Wt[u][kk] = (u < U_) ? Sbase[(size_t)u * 1024 + kt * 64 + kk] : 0.f;
        }
        __syncthreads();
#pragma unroll 2
        for (int kk = 0; kk < 64; ++kk) {
            float vv = Vs[kk][td];
#pragma unroll
            for (int j = 0; j < 9; j++) acc[j] = fmaf(Wt[tg + 4 * j][kk], vv, acc[j]);
        }
    }
#pragma unroll
    for (int j = 0; j < 9; j++) {
        int u = tg + 4 * j;
        if (u < U_) ctx[((size_t)bh * U_ + u) * 64 + td] = acc[j];
    }
}

// ---------------------------------------------------------------
// x[b][l][h*64+d] = vmean[b*8+h][d]
// ---------------------------------------------------------------
__global__ void fill_x_kernel(const float* __restrict__ vmean, float* __restrict__ x)
{
    const size_t i = (size_t)blockIdx.x * 256 + threadIdx.x;
    const int n = (int)(i & 511);
    const int b = (int)(i >> 19);
    x[i] = vmean[((b << 3) + (n >> 6)) * 64 + (n & 63)];
}

// ---------------------------------------------------------------
// scatter ctx rows into x ; grid 4480, block 64
// ---------------------------------------------------------------
__global__ void scatter_ctx_kernel(const float* __restrict__ ctx, const int* __restrict__ idx,
                                   float* __restrict__ x)
{
    const int r = blockIdx.x;
    const int bh = r / U_;
    const int b = bh >> 3, h = bh & 7;
    const int l = idx[r];
    x[(((size_t)b * L_ + l) << 9) + (h << 6) + threadIdx.x] = ctx[(size_t)r * 64 + threadIdx.x];
}

// ---------------------------------------------------------------
extern "C" void kernel_launch(void* const* d_in, const int* in_sizes, int n_in,
                              void* d_out, int out_size, void* d_ws, size_t ws_size,
                              hipStream_t stream)
{
    (void)in_sizes; (void)n_in; (void)out_size; (void)ws_size;
    const float* query = (const float*)d_in[0];
    const float* key   = (const float*)d_in[1];
    const float* value = (const float*)d_in[2];
    const int*   mask  = (const int*)d_in[3];
    const float* Wq = (const float*)d_in[4];
    const float* bq = (const float*)d_in[5];
    const float* Wk = (const float*)d_in[6];
    const float* bk = (const float*)d_in[7];
    const float* Wv = (const float*)d_in[8];
    const float* bvp = (const float*)d_in[9];
    const float* Wo = (const float*)d_in[10];
    const float* bo = (const float*)d_in[11];
    float* out = (float*)d_out;

    float* ws = (float*)d_ws;
    float* v      = ws + OFF_V;
    unsigned short* q_hi = (unsigned short*)(ws + OFF_QHI);
    unsigned short* q_lo = (unsigned short*)(ws + OFF_QLO);
    unsigned short* k_hi = (unsigned short*)(ws + OFF_KHI);
    unsigned short* k_lo = (unsigned short*)(ws + OFF_KLO);
    float* x      = ws + OFF_X;
    float* S      = ws + OFF_S;
    float* Marr   = ws + OFF_M;
    float* kmean  = ws + OFF_KMEAN;
    float* vmean  = ws + OFF_VMEAN;
    float* ctx    = ws + OFF_CTX;
    int*   idx    = (int*)(ws + OFF_IDX);
    unsigned short* wqh = (unsigned short*)(ws + OFF_WQH);
    unsigned short* wql = (unsigned short*)(ws + OFF_WQL);
    unsigned short* wkh = (unsigned short*)(ws + OFF_WKH);
    unsigned short* wkl = (unsigned short*)(ws + OFF_WKL);
    unsigned short* wvh = (unsigned short*)(ws + OFF_WVH);
    unsigned short* wvl = (unsigned short*)(ws + OFF_WVL);
    unsigned short* woh = (unsigned short*)(ws + OFF_WOH);
    unsigned short* wol = (unsigned short*)(ws + OFF_WOL);

    // weight splits
    split_w_kernel<<<1024, 256, 0, stream>>>(Wq, wqh, wql);
    split_w_kernel<<<1024, 256, 0, stream>>>(Wk, wkh, wkl);
    split_w_kernel<<<1024, 256, 0, stream>>>(Wv, wvh, wvl);
    split_w_kernel<<<1024, 256, 0, stream>>>(Wo, woh, wol);

    // projections (bf16x2 MFMA); q,k emit hi/lo bf16, v emits fp32
    const dim3 ggemm(128, 4);
    gemm_mfma<<<ggemm, 256, 0, stream>>>(query, wqh, wql, bq, nullptr, q_hi, q_lo, 1);
    gemm_mfma<<<ggemm, 256, 0, stream>>>(key,   wkh, wkl, bk, nullptr, k_hi, k_lo, 1);
    gemm_mfma<<<ggemm, 256, 0, stream>>>(value, wvh, wvl, bvp, v, nullptr, nullptr, 1);

    // per-(b,h) means
    mean_over_L_bf<<<128, 256, 0, stream>>>(k_hi, k_lo, kmean);
    mean_over_L<<<128, 256, 0, stream>>>(v, vmean);

    // sparsity measure M (MFMA) and top-35
    qk_rowmax_mfma<<<dim3(16, 128), 256, 0, stream>>>(q_hi, q_lo, k_hi, k_lo, kmean, Marr);
    topk35<<<128, 256, 0, stream>>>(Marr, idx);

    // reduced attention
    scores_red<<<128, 256, 0, stream>>>(q_hi, q_lo, k_hi, k_lo, idx, mask, S);
    softmax_rows<<<B_ * H_ * U_, 256, 0, stream>>>(S);
    ctx_gemm<<<128, 256, 0, stream>>>(S, v, ctx);

    // assemble x (overwrites q_hi/q_lo region) and final projection
    fill_x_kernel<<<32768, 256, 0, stream>>>(vmean, x);
    scatter_ctx_kernel<<<B_ * H_ * U_, 64, 0, stream>>>(ctx, idx, x);
    gemm_mfma<<<ggemm, 256, 0, stream>>>(x, woh, wol, bo, out, nullptr, nullptr, 0);
}

// Round 4
// 510.443 us; speedup vs baseline: 2.1468x; 1.2187x over previous
//
#include <hip/hip_runtime.h>
#include <math.h>

#define B_ 16
#define L_ 1024
#define H_ 8
#define U_ 35

typedef float f32x4 __attribute__((ext_vector_type(4)));
typedef short bf16x8 __attribute__((ext_vector_type(8)));

__device__ __forceinline__ unsigned short f2bf(float x) {
    unsigned int u = __float_as_uint(x);
    u += 0x7FFFu + ((u >> 16) & 1u);      // round-to-nearest-even
    return (unsigned short)(u >> 16);
}
__device__ __forceinline__ float bf2f(unsigned short b) {
    return __uint_as_float(((unsigned int)b) << 16);
}

#define MFMA(a, b, c) __builtin_amdgcn_mfma_f32_16x16x32_bf16((a), (b), (c), 0, 0, 0)

// ---------------- workspace layout (float-element offsets) ----------------
#define OFF_V      ((size_t)0)           // 8388608 f
#define OFF_QHI    ((size_t)8388608)     // 4194304
#define OFF_QLO    ((size_t)12582912)    // 4194304
#define OFF_X      OFF_QHI               // x fp32 aliases q_hi/q_lo (dead then)
#define OFF_CTXP   OFF_QHI               // ctx partials alias q_hi (dead after scores)
#define OFF_KHI    ((size_t)16777216)    // 4194304
#define OFF_KLO    ((size_t)20971520)    // 4194304
#define OFF_S      ((size_t)25165824)    // 4587520
#define OFF_WQH    OFF_S                 // W splits alias S (dead before scores)
#define OFF_WQL    ((size_t)(OFF_S + 131072))
#define OFF_WKH    ((size_t)(OFF_S + 262144))
#define OFF_WKL    ((size_t)(OFF_S + 393216))
#define OFF_WVH    ((size_t)(OFF_S + 524288))
#define OFF_WVL    ((size_t)(OFF_S + 655360))
#define OFF_M      ((size_t)29753344)    // 131072
#define OFF_KMEAN  ((size_t)29884416)    // 8192
#define OFF_VMEAN  ((size_t)29892608)    // 8192
#define OFF_CTX    ((size_t)29900800)    // 286720
#define OFF_IDX    ((size_t)30187520)    // 4480
#define OFF_WOH    ((size_t)30192000)    // 131072
#define OFF_WOL    ((size_t)30323072)    // 131072
// end 30454144 f = ~121.8 MB

// ---------------------------------------------------------------
// split one 512x512 fp32 weight into hi/lo bf16 bits; grid 1024 x 256
// ---------------------------------------------------------------
__global__ __launch_bounds__(256) void split_w_kernel(
    const float* __restrict__ W, unsigned short* __restrict__ hi,
    unsigned short* __restrict__ lo)
{
    int i = blockIdx.x * 256 + threadIdx.x;
    float x = W[i];
    unsigned short h = f2bf(x);
    hi[i] = h;
    lo[i] = f2bf(x - bf2f(h));
}

// ---------------------------------------------------------------
// bf16x2 MFMA GEMM: C[m,n] = sum_k A[m,k]*W[n,k] + bias[n]
// ---------------------------------------------------------------
__global__ __launch_bounds__(256) void gemm_mfma(
    const float* __restrict__ A,
    const unsigned short* __restrict__ Whi, const unsigned short* __restrict__ Wlo,
    const float* __restrict__ bias,
    float* __restrict__ outf,
    unsigned short* __restrict__ ohi, unsigned short* __restrict__ olo,
    const int head_layout)
{
    __shared__ unsigned short Ah[128][40];
    __shared__ unsigned short Al[128][40];
    __shared__ unsigned short Bh[128][40];
    __shared__ unsigned short Bl[128][40];
    const int tid = threadIdx.x, lane = tid & 63, wave = tid >> 6;
    const int m0 = blockIdx.x * 128, n0 = blockIdx.y * 128;
    const int wm = (wave >> 1) * 64, wn = (wave & 1) * 64;

    f32x4 zero4 = {0.f, 0.f, 0.f, 0.f};
    f32x4 acc[4][4];
#pragma unroll
    for (int i = 0; i < 4; i++)
#pragma unroll
        for (int j = 0; j < 4; j++) acc[i][j] = zero4;

    const int ar = tid >> 3, ac = (tid & 7) * 4;
    const int br = tid >> 2, bc = (tid & 3) * 8;
    const int kc = (lane >> 4) * 8;
    const int fr = lane & 15;

    for (int k0 = 0; k0 < 512; k0 += 32) {
        if (k0) __syncthreads();
#pragma unroll
        for (int p = 0; p < 4; ++p) {
            float4 a4 = *(const float4*)(A + (size_t)(m0 + ar + p * 32) * 512 + k0 + ac);
            ushort4 h4, l4;
            h4.x = f2bf(a4.x); l4.x = f2bf(a4.x - bf2f(h4.x));
            h4.y = f2bf(a4.y); l4.y = f2bf(a4.y - bf2f(h4.y));
            h4.z = f2bf(a4.z); l4.z = f2bf(a4.z - bf2f(h4.z));
            h4.w = f2bf(a4.w); l4.w = f2bf(a4.w - bf2f(h4.w));
            *(ushort4*)&Ah[ar + p * 32][ac] = h4;
            *(ushort4*)&Al[ar + p * 32][ac] = l4;
        }
#pragma unroll
        for (int p = 0; p < 2; ++p) {
            size_t off = (size_t)(n0 + br + p * 64) * 512 + k0 + bc;
            *(uint4*)&Bh[br + p * 64][bc] = *(const uint4*)(Whi + off);
            *(uint4*)&Bl[br + p * 64][bc] = *(const uint4*)(Wlo + off);
        }
        __syncthreads();

        bf16x8 ah[4], al[4];
#pragma unroll
        for (int mi = 0; mi < 4; ++mi) {
            int row = wm + mi * 16 + fr;
            ah[mi] = *(bf16x8*)&Ah[row][kc];
            al[mi] = *(bf16x8*)&Al[row][kc];
        }
#pragma unroll
        for (int ni = 0; ni < 4; ++ni) {
            int rn = wn + ni * 16 + fr;
            bf16x8 bh8 = *(bf16x8*)&Bh[rn][kc];
            bf16x8 bl8 = *(bf16x8*)&Bl[rn][kc];
#pragma unroll
            for (int mi = 0; mi < 4; ++mi) {
                acc[mi][ni] = MFMA(ah[mi], bh8, acc[mi][ni]);
                acc[mi][ni] = MFMA(ah[mi], bl8, acc[mi][ni]);
                acc[mi][ni] = MFMA(al[mi], bh8, acc[mi][ni]);
            }
        }
    }

    const int col = lane & 15, rq = (lane >> 4) * 4;
#pragma unroll
    for (int ni = 0; ni < 4; ++ni) {
        int n = n0 + wn + ni * 16 + col;
        float bn = bias[n];
#pragma unroll
        for (int mi = 0; mi < 4; ++mi) {
#pragma unroll
            for (int r = 0; r < 4; ++r) {
                int m = m0 + wm + mi * 16 + rq + r;
                float val = acc[mi][ni][r] + bn;
                if (head_layout) {
                    size_t off = ((size_t)((m >> 10) * H_ + (n >> 6)) * L_ + (m & 1023)) * 64 + (n & 63);
                    if (outf) outf[off] = val;
                    if (ohi) {
                        unsigned short h = f2bf(val);
                        ohi[off] = h;
                        olo[off] = f2bf(val - bf2f(h));
                    }
                } else {
                    outf[(size_t)m * 512 + n] = val;
                }
            }
        }
    }
}

// ---------------------------------------------------------------
// mean over L of fp32 [bh][l][d] -> [bh][d]
// ---------------------------------------------------------------
__global__ __launch_bounds__(256) void mean_over_L(
    const float* __restrict__ src, float* __restrict__ dst)
{
    const int bh = blockIdx.x;
    const int d = threadIdx.x & 63, g = threadIdx.x >> 6;
    const float* p = src + ((size_t)bh * L_ + g * 256) * 64 + d;
    float s = 0.f;
#pragma unroll 8
    for (int l = 0; l < 256; l++) s += p[(size_t)l * 64];
    __shared__ float red[4][64];
    red[g][d] = s;
    __syncthreads();
    if (threadIdx.x < 64) {
        const int dd = threadIdx.x;
        dst[(size_t)bh * 64 + dd] =
            (red[0][dd] + red[1][dd] + red[2][dd] + red[3][dd]) * (1.0f / 1024.0f);
    }
}

__global__ __launch_bounds__(256) void mean_over_L_bf(
    const unsigned short* __restrict__ hi, const unsigned short* __restrict__ lo,
    float* __restrict__ dst)
{
    const int bh = blockIdx.x;
    const int d = threadIdx.x & 63, g = threadIdx.x >> 6;
    size_t base = ((size_t)bh * L_ + g * 256) * 64 + d;
    float s = 0.f;
#pragma unroll 8
    for (int l = 0; l < 256; l++) {
        size_t o = base + (size_t)l * 64;
        s += bf2f(hi[o]) + bf2f(lo[o]);
    }
    __shared__ float red[4][64];
    red[g][d] = s;
    __syncthreads();
    if (threadIdx.x < 64) {
        const int dd = threadIdx.x;
        dst[(size_t)bh * 64 + dd] =
            (red[0][dd] + red[1][dd] + red[2][dd] + red[3][dd]) * (1.0f / 1024.0f);
    }
}

// ---------------------------------------------------------------
// M[l] = max_k(q_l . k_k) - q_l . kmean via bf16x2 MFMA
// ---------------------------------------------------------------
__global__ __launch_bounds__(256) void qk_rowmax_mfma(
    const unsigned short* __restrict__ qhi, const unsigned short* __restrict__ qlo,
    const unsigned short* __restrict__ khi, const unsigned short* __restrict__ klo,
    const float* __restrict__ kmean, float* __restrict__ Mout)
{
    __shared__ unsigned short Qh[64][72], Ql[64][72];
    __shared__ unsigned short Kh[128][72], Kl[128][72];
    __shared__ float Mred[64][4];
    __shared__ float km[64];
    const int bh = blockIdx.y, q0 = blockIdx.x * 64;
    const int tid = threadIdx.x, lane = tid & 63, wave = tid >> 6;

    if (tid < 64) km[tid] = kmean[bh * 64 + tid];
    {
        int r = tid >> 2, c = (tid & 3) * 16;
        size_t off = ((size_t)bh * L_ + q0 + r) * 64 + c;
        *(uint4*)&Qh[r][c]     = *(const uint4*)(qhi + off);
        *(uint4*)&Qh[r][c + 8] = *(const uint4*)(qhi + off + 8);
        *(uint4*)&Ql[r][c]     = *(const uint4*)(qlo + off);
        *(uint4*)&Ql[r][c + 8] = *(const uint4*)(qlo + off + 8);
    }

    float rmax[4][4];
#pragma unroll
    for (int mi = 0; mi < 4; ++mi)
#pragma unroll
        for (int r = 0; r < 4; ++r) rmax[mi][r] = -INFINITY;

    const size_t kb = (size_t)bh * L_ * 64;
    const int sr = tid >> 2, sc = (tid & 3) * 16;
    const int fr = lane & 15;
    f32x4 zero4 = {0.f, 0.f, 0.f, 0.f};

    for (int kt = 0; kt < 8; ++kt) {
        __syncthreads();
        {
            size_t off = kb + (size_t)(kt * 128 + sr) * 64 + sc;
            *(uint4*)&Kh[sr][sc]          = *(const uint4*)(khi + off);
            *(uint4*)&Kh[sr][sc + 8]      = *(const uint4*)(khi + off + 8);
            *(uint4*)&Kl[sr][sc]          = *(const uint4*)(klo + off);
            *(uint4*)&Kl[sr][sc + 8]      = *(const uint4*)(klo + off + 8);
            size_t off2 = off + 64 * 64;
            *(uint4*)&Kh[sr + 64][sc]     = *(const uint4*)(khi + off2);
            *(uint4*)&Kh[sr + 64][sc + 8] = *(const uint4*)(khi + off2 + 8);
            *(uint4*)&Kl[sr + 64][sc]     = *(const uint4*)(klo + off2);
            *(uint4*)&Kl[sr + 64][sc + 8] = *(const uint4*)(klo + off2 + 8);
        }
        __syncthreads();

        f32x4 acc[4][2];
#pragma unroll
        for (int mi = 0; mi < 4; ++mi) { acc[mi][0] = zero4; acc[mi][1] = zero4; }

#pragma unroll
        for (int ks = 0; ks < 2; ++ks) {
            int kcol = ks * 32 + (lane >> 4) * 8;
            bf16x8 ah[4], al[4];
#pragma unroll
            for (int mi = 0; mi < 4; ++mi) {
                int row = mi * 16 + fr;
                ah[mi] = *(bf16x8*)&Qh[row][kcol];
                al[mi] = *(bf16x8*)&Ql[row][kcol];
            }
#pragma unroll
            for (int ni = 0; ni < 2; ++ni) {
                int krow = wave * 32 + ni * 16 + fr;
                bf16x8 bh8 = *(bf16x8*)&Kh[krow][kcol];
                bf16x8 bl8 = *(bf16x8*)&Kl[krow][kcol];
#pragma unroll
                for (int mi = 0; mi < 4; ++mi) {
                    acc[mi][ni] = MFMA(ah[mi], bh8, acc[mi][ni]);
                    acc[mi][ni] = MFMA(ah[mi], bl8, acc[mi][ni]);
                    acc[mi][ni] = MFMA(al[mi], bh8, acc[mi][ni]);
                }
            }
        }
#pragma unroll
        for (int mi = 0; mi < 4; ++mi)
#pragma unroll
            for (int r = 0; r < 4; ++r)
                rmax[mi][r] = fmaxf(rmax[mi][r], fmaxf(acc[mi][0][r], acc[mi][1][r]));
    }

#pragma unroll
    for (int mi = 0; mi < 4; ++mi)
#pragma unroll
        for (int r = 0; r < 4; ++r) {
            float v = rmax[mi][r];
            v = fmaxf(v, __shfl_xor(v, 1));
            v = fmaxf(v, __shfl_xor(v, 2));
            v = fmaxf(v, __shfl_xor(v, 4));
            v = fmaxf(v, __shfl_xor(v, 8));
            rmax[mi][r] = v;
        }
    if ((lane & 15) == 0) {
        int quad = lane >> 4;
#pragma unroll
        for (int mi = 0; mi < 4; ++mi)
#pragma unroll
            for (int r = 0; r < 4; ++r)
                Mred[mi * 16 + quad * 4 + r][wave] = rmax[mi][r];
    }
    __syncthreads();
    if (tid < 64) {
        float mx = fmaxf(fmaxf(Mred[tid][0], Mred[tid][1]),
                         fmaxf(Mred[tid][2], Mred[tid][3]));
        float dot = 0.f;
#pragma unroll 4
        for (int d = 0; d < 64; ++d)
            dot = fmaf(bf2f(Qh[tid][d]) + bf2f(Ql[tid][d]), km[d], dot);
        Mout[(size_t)bh * L_ + q0 + tid] = mx - dot;
    }
}

// ---------------------------------------------------------------
// top-35 of M[1024] per (b,h)
// ---------------------------------------------------------------
__global__ __launch_bounds__(256) void topk35(
    const float* __restrict__ Min, int* __restrict__ idx_out)
{
    const int bh = blockIdx.x;
    const int tid = threadIdx.x;
    __shared__ float vals[1024];
    __shared__ float wv[4];
    __shared__ int wi[4];
    for (int i = tid; i < 1024; i += 256) vals[i] = Min[(size_t)bh * 1024 + i];
    __syncthreads();
    for (int it = 0; it < U_; ++it) {
        float bv = -INFINITY; int bi = 1 << 30;
        for (int i = tid; i < 1024; i += 256) {
            float x = vals[i];
            if (x > bv) { bv = x; bi = i; }
        }
#pragma unroll
        for (int off = 32; off; off >>= 1) {
            float ov = __shfl_down(bv, off);
            int   oi = __shfl_down(bi, off);
            if (ov > bv || (ov == bv && oi < bi)) { bv = ov; bi = oi; }
        }
        if ((tid & 63) == 0) { wv[tid >> 6] = bv; wi[tid >> 6] = bi; }
        __syncthreads();
        if (tid == 0) {
#pragma unroll
            for (int w = 1; w < 4; ++w) {
                if (wv[w] > bv || (wv[w] == bv && wi[w] < bi)) { bv = wv[w]; bi = wi[w]; }
            }
            idx_out[bh * U_ + it] = bi;
            vals[bi] = -INFINITY;
        }
        __syncthreads();
    }
}

// ---------------------------------------------------------------
// S[u][k] = (q[idx_u] . k_k)/8 masked; grid (128 bh, 8 key-chunks)
// ---------------------------------------------------------------
__global__ __launch_bounds__(256) void scores_red(
    const unsigned short* __restrict__ qhi, const unsigned short* __restrict__ qlo,
    const unsigned short* __restrict__ khi, const unsigned short* __restrict__ klo,
    const int* __restrict__ idx, const int* __restrict__ mask,
    float* __restrict__ S)
{
    __shared__ float Qs[64][36];
    __shared__ float Ks[64][68];
    const int bh = blockIdx.x;
    const int b = bh >> 3;
    const int tid = threadIdx.x;
    const int tk = tid & 63, tg = tid >> 6;

    for (int t = tid; t < 36 * 64; t += 256) {
        int u = t >> 6, d = t & 63;
        float val = 0.f;
        if (u < U_) {
            int l = idx[bh * U_ + u];
            size_t off = ((size_t)bh * L_ + l) * 64 + d;
            val = bf2f(qhi[off]) + bf2f(qlo[off]);
        }
        Qs[d][u] = val;
    }

    const size_t kb = (size_t)bh * L_ * 64;
    const int sr = tid >> 2, sc = (tid & 3) * 16;
    float acc[9];
    const int kt0 = blockIdx.y * 2;
    for (int ki = 0; ki < 2; ++ki) {
        int kt = kt0 + ki;
        if (ki) __syncthreads();
        {
            size_t off = kb + (size_t)(kt * 64 + sr) * 64 + sc;
            uint4 h0 = *(const uint4*)(khi + off);
            uint4 h1 = *(const uint4*)(khi + off + 8);
            uint4 l0 = *(const uint4*)(klo + off);
            uint4 l1 = *(const uint4*)(klo + off + 8);
            unsigned short hv[16], lv[16];
            *(uint4*)hv = h0; *(uint4*)(hv + 8) = h1;
            *(uint4*)lv = l0; *(uint4*)(lv + 8) = l1;
#pragma unroll
            for (int i = 0; i < 16; ++i)
                Ks[sc + i][sr] = bf2f(hv[i]) + bf2f(lv[i]);
        }
        __syncthreads();
#pragma unroll
        for (int j = 0; j < 9; j++) acc[j] = 0.f;
#pragma unroll 4
        for (int d = 0; d < 64; ++d) {
            float kv = Ks[d][tk];
#pragma unroll
            for (int j = 0; j < 9; j++) acc[j] = fmaf(Qs[d][tg + 4 * j], kv, acc[j]);
        }
        const int kcol = kt * 64 + tk;
        const bool msk = (mask[b * L_ + kcol] == 0);
#pragma unroll
        for (int j = 0; j < 9; j++) {
            int u = tg + 4 * j;
            if (u < U_)
                S[((size_t)bh * U_ + u) * 1024 + kcol] = msk ? -INFINITY : acc[j] * 0.125f;
        }
    }
}

// ---------------------------------------------------------------
// softmax over 1024 per row; grid 4480 rows
// ---------------------------------------------------------------
__global__ __launch_bounds__(256) void softmax_rows(float* __restrict__ S)
{
    const size_t base = (size_t)blockIdx.x * 1024;
    const int tid = threadIdx.x;
    __shared__ float redm[4];
    __shared__ float reds[4];
    float4 v = *(const float4*)(S + base + tid * 4);
    float mx = fmaxf(fmaxf(v.x, v.y), fmaxf(v.z, v.w));
#pragma unroll
    for (int off = 32; off; off >>= 1) mx = fmaxf(mx, __shfl_down(mx, off));
    if ((tid & 63) == 0) redm[tid >> 6] = mx;
    __syncthreads();
    mx = fmaxf(fmaxf(redm[0], redm[1]), fmaxf(redm[2], redm[3]));
    float e0 = __expf(v.x - mx), e1 = __expf(v.y - mx);
    float e2 = __expf(v.z - mx), e3 = __expf(v.w - mx);
    float s = e0 + e1 + e2 + e3;
#pragma unroll
    for (int off = 32; off; off >>= 1) s += __shfl_down(s, off);
    if ((tid & 63) == 0) reds[tid >> 6] = s;
    __syncthreads();
    s = reds[0] + reds[1] + reds[2] + reds[3];
    const float inv = 1.0f / s;
    float4 o; o.x = e0 * inv; o.y = e1 * inv; o.z = e2 * inv; o.w = e3 * inv;
    *(float4*)(S + base + tid * 4) = o;
}

// ---------------------------------------------------------------
// ctx partials: ctxp[kc][bh][u][d] = sum over 128 keys of chunk kc
// grid (128 bh, 8 kc)
// ---------------------------------------------------------------
__global__ __launch_bounds__(256) void ctx_partial(
    const float* __restrict__ S, const float* __restrict__ v,
    float* __restrict__ ctxp)
{
    __shared__ float Vs[128][68];
    __shared__ float Wt[36][128];
    const int bh = blockIdx.x, kc = blockIdx.y;
    const int tid = threadIdx.x;
    const int td = tid & 63, tg = tid >> 6;
    const int lr = tid >> 2, lc0 = (tid & 3) * 16;

    const float* vbase = v + ((size_t)bh * L_ + kc * 128) * 64;
    const float* Sbase = S + (size_t)bh * U_ * 1024 + kc * 128;

#pragma unroll
    for (int hh = 0; hh < 2; ++hh) {
        int row = lr + hh * 64;
        const float* src = vbase + (size_t)row * 64 + lc0;
        *(float4*)&Vs[row][lc0 + 0]  = *(const float4*)(src + 0);
        *(float4*)&Vs[row][lc0 + 4]  = *(const float4*)(src + 4);
        *(float4*)&Vs[row][lc0 + 8]  = *(const float4*)(src + 8);
        *(float4*)&Vs[row][lc0 + 12] = *(const float4*)(src + 12);
    }
    for (int t = tid; t < 36 * 128; t += 256) {
        int u = t >> 7, kk = t & 127;
        Wt[u][kk] = (u < U_) ? Sbase[(size_t)u * 1024 + kk] : 0.f;
    }
    __syncthreads();

    float acc[9];
#pragma unroll
    for (int j = 0; j < 9; j++) acc[j] = 0.f;
#pragma unroll 2
    for (int kk = 0; kk < 128; ++kk) {
        float vv = Vs[kk][td];
#pragma unroll
        for (int j = 0; j < 9; j++) acc[j] = fmaf(Wt[tg + 4 * j][kk], vv, acc[j]);
    }
#pragma unroll
    for (int j = 0; j < 9; j++) {
        int u = tg + 4 * j;
        if (u < U_)
            ctxp[((size_t)(kc * 128 + bh) * 36 + u) * 64 + td] = acc[j];
    }
}

// ---------------------------------------------------------------
// ctx[bh][u][d] = sum_kc ctxp[kc][bh][u][d] ; grid 1120 x 256
// ---------------------------------------------------------------
__global__ __launch_bounds__(256) void ctx_reduce(
    const float* __restrict__ ctxp, float* __restrict__ ctx)
{
    const int i = blockIdx.x * 256 + threadIdx.x;   // 128*35*64 = 286720
    const int d = i & 63;
    const int rest = i >> 6;
    const int u = rest % U_;
    const int bh = rest / U_;
    float s = 0.f;
#pragma unroll
    for (int kc = 0; kc < 8; ++kc)
        s += ctxp[((size_t)(kc * 128 + bh) * 36 + u) * 64 + d];
    ctx[i] = s;
}

// ---------------------------------------------------------------
// x[b][l][h*64+d] = vmean[b*8+h][d]
// ---------------------------------------------------------------
__global__ void fill_x_kernel(const float* __restrict__ vmean, float* __restrict__ x)
{
    const size_t i = (size_t)blockIdx.x * 256 + threadIdx.x;
    const int n = (int)(i & 511);
    const int b = (int)(i >> 19);
    x[i] = vmean[((b << 3) + (n >> 6)) * 64 + (n & 63)];
}

// ---------------------------------------------------------------
// scatter ctx rows into x ; grid 4480, block 64
// ---------------------------------------------------------------
__global__ void scatter_ctx_kernel(const float* __restrict__ ctx, const int* __restrict__ idx,
                                   float* __restrict__ x)
{
    const int r = blockIdx.x;
    const int bh = r / U_;
    const int b = bh >> 3, h = bh & 7;
    const int l = idx[r];
    x[(((size_t)b * L_ + l) << 9) + (h << 6) + threadIdx.x] = ctx[(size_t)r * 64 + threadIdx.x];
}

// ---------------------------------------------------------------
extern "C" void kernel_launch(void* const* d_in, const int* in_sizes, int n_in,
                              void* d_out, int out_size, void* d_ws, size_t ws_size,
                              hipStream_t stream)
{
    (void)in_sizes; (void)n_in; (void)out_size; (void)ws_size;
    const float* query = (const float*)d_in[0];
    const float* key   = (const float*)d_in[1];
    const float* value = (const float*)d_in[2];
    const int*   mask  = (const int*)d_in[3];
    const float* Wq = (const float*)d_in[4];
    const float* bq = (const float*)d_in[5];
    const float* Wk = (const float*)d_in[6];
    const float* bk = (const float*)d_in[7];
    const float* Wv = (const float*)d_in[8];
    const float* bvp = (const float*)d_in[9];
    const float* Wo = (const float*)d_in[10];
    const float* bo = (const float*)d_in[11];
    float* out = (float*)d_out;

    float* ws = (float*)d_ws;
    float* v      = ws + OFF_V;
    unsigned short* q_hi = (unsigned short*)(ws + OFF_QHI);
    unsigned short* q_lo = (unsigned short*)(ws + OFF_QLO);
    unsigned short* k_hi = (unsigned short*)(ws + OFF_KHI);
    unsigned short* k_lo = (unsigned short*)(ws + OFF_KLO);
    float* x      = ws + OFF_X;
    float* ctxp   = ws + OFF_CTXP;
    float* S      = ws + OFF_S;
    float* Marr   = ws + OFF_M;
    float* kmean  = ws + OFF_KMEAN;
    float* vmean  = ws + OFF_VMEAN;
    float* ctx    = ws + OFF_CTX;
    int*   idx    = (int*)(ws + OFF_IDX);
    unsigned short* wqh = (unsigned short*)(ws + OFF_WQH);
    unsigned short* wql = (unsigned short*)(ws + OFF_WQL);
    unsigned short* wkh = (unsigned short*)(ws + OFF_WKH);
    unsigned short* wkl = (unsigned short*)(ws + OFF_WKL);
    unsigned short* wvh = (unsigned short*)(ws + OFF_WVH);
    unsigned short* wvl = (unsigned short*)(ws + OFF_WVL);
    unsigned short* woh = (unsigned short*)(ws + OFF_WOH);
    unsigned short* wol = (unsigned short*)(ws + OFF_WOL);

    // weight splits
    split_w_kernel<<<1024, 256, 0, stream>>>(Wq, wqh, wql);
    split_w_kernel<<<1024, 256, 0, stream>>>(Wk, wkh, wkl);
    split_w_kernel<<<1024, 256, 0, stream>>>(Wv, wvh, wvl);
    split_w_kernel<<<1024, 256, 0, stream>>>(Wo, woh, wol);

    // projections (bf16x2 MFMA); q,k emit hi/lo bf16, v emits fp32
    const dim3 ggemm(128, 4);
    gemm_mfma<<<ggemm, 256, 0, stream>>>(query, wqh, wql, bq, nullptr, q_hi, q_lo, 1);
    gemm_mfma<<<ggemm, 256, 0, stream>>>(key,   wkh, wkl, bk, nullptr, k_hi, k_lo, 1);
    gemm_mfma<<<ggemm, 256, 0, stream>>>(value, wvh, wvl, bvp, v, nullptr, nullptr, 1);

    // per-(b,h) means
    mean_over_L_bf<<<128, 256, 0, stream>>>(k_hi, k_lo, kmean);
    mean_over_L<<<128, 256, 0, stream>>>(v, vmean);

    // sparsity measure M (MFMA) and top-35
    qk_rowmax_mfma<<<dim3(16, 128), 256, 0, stream>>>(q_hi, q_lo, k_hi, k_lo, kmean, Marr);
    topk35<<<128, 256, 0, stream>>>(Marr, idx);

    // reduced attention (K-split for parallelism)
    scores_red<<<dim3(128, 8), 256, 0, stream>>>(q_hi, q_lo, k_hi, k_lo, idx, mask, S);
    softmax_rows<<<B_ * H_ * U_, 256, 0, stream>>>(S);
    ctx_partial<<<dim3(128, 8), 256, 0, stream>>>(S, v, ctxp);   // ctxp aliases q_hi (dead)
    ctx_reduce<<<1120, 256, 0, stream>>>(ctxp, ctx);

    // assemble x (overwrites q_hi/q_lo region) and final projection
    fill_x_kernel<<<32768, 256, 0, stream>>>(vmean, x);
    scatter_ctx_kernel<<<B_ * H_ * U_, 64, 0, stream>>>(ctx, idx, x);
    gemm_mfma<<<ggemm, 256, 0, stream>>>(x, woh, wol, bo, out, nullptr, nullptr, 0);
}